// Round 2
// baseline (103.914 us; speedup 1.0000x reference)
//
#include <hip/hip_runtime.h>

// SimplePitchEstimator on MI355X (gfx950).
// ac = irfft(rfft(x,512)^2) == linear self-convolution c[n] = sum y[i]y[n-i],
// y = x - mean(x). Round-14: intra-block 2-pass software pipeline.
//
// Evidence chain: r12 = 97.17us total = 2x ~42.5us harness poison fills
// (immutable) + ~12.1us pitch_kernel (~= 6.7us HBM + 6.1us per-SIMD VALU,
// back-to-back). r13's s_sleep cross-block stagger REGRESSED +3.9us (= the
// sleep offset, zero overlap gained) -> cross-block scheduling via assumed
// dispatch mapping refuted. This round: guaranteed intra-block overlap.
// 512 blocks x 128 frames, 2 passes of 64 frames; ALL 20 float4 global
// loads issued at kernel entry. Pass-0's 10 are waited at its mean
// (vmcnt), pass-1's 10 stay in flight through pass-0's entire conv
// (~3us VALU issue >> HBM service) and are waited at pass-1's mean.
// Loads can't sink: __syncthreads clobbers memory in LLVM's model.
// +40 VGPR staged across conv-0 (~150 peak, <256 = 2-wave/SIMD cliff).
// Predicted kernel 12.1 -> ~10.5-11us, dur_us 97.2 -> 95-96.5.
//
//  * Six NAMED float4 vars W0..W5 hold the 6 window quads; quad->var map
//    (quad % 6) repeats every 6 rounds -> clean loop unrolled x6; every
//    reference is a static component of a named var (no array).
//  * Refill ds_read_b128 directly into the rotating target var, placed
//    after the round's FMAs (latency covered by next round); x quads via
//    2-var ping-pong (trip length 6 even -> static parity).
//  * Remainder + ragged rounds statically unrolled, affine masks
//    8r+2d < N0+j.
//  * Half-sum c[n] = 2*sum_{2i<n} y_i y_{n-i} + center (validated r6-r10).
//  * LDS 160x64x4 = 40960 B (one frame-set); aux rows reused per pass;
//    balanced tile pairs 27/27/28/28; mu folded at LDS write; silent-check
//    pm rides in a register to the final reduction.

#define SR_F    16000.0f
#define HOPSZ   256
#define TFRAMES 4096
#define SAMPLES 1048576

#define CMP(v_, c_) ((c_) == 0 ? (v_).x : (c_) == 1 ? (v_).y : \
                     (c_) == 2 ? (v_).z : (v_).w)

template<int N0>
__device__ __forceinline__ void conv_tile(const float4* __restrict__ col4,
                                          const float* __restrict__ colf,
                                          float& best, int& bl) {
    constexpr int J    = 15;
    constexpr int B0   = ((N0 - 3) / 4) * 4;   // aligned window base row
    constexpr int Q0   = B0 / 4;               // base quad at round 0
    constexpr int KOFF = N0 - B0;              // 3..6
    constexpr int IC   = (N0 + J) / 2;         // i-count for max lag
    constexpr int RT   = (IC + 3) / 4;         // total rounds
    constexpr int RC   = (N0 - 6 + 7) / 8;     // clean rounds (8r+6 < N0)
    constexpr int T    = RC / 6;               // runtime x6 trips
    constexpr int R6   = 6 * T;                // first static round
    static_assert(KOFF >= 3 && KOFF + J - 1 <= 20, "window index bound");
    static_assert(RC >= 1 && RC <= RT - 1, "clean/ragged split");
    static_assert(Q0 - RT + 1 >= 0, "refill quad in range");

    float acc[J];
    #pragma unroll
    for (int j = 0; j < J; ++j) acc[j] = 0.f;

    float4 W0_, W1_, W2_, W3_, W4_, W5_, xa_, xb_;

#define WREAD(vi_, c_) \
    ((vi_) == 0 ? CMP(W0_, c_) : (vi_) == 1 ? CMP(W1_, c_) : \
     (vi_) == 2 ? CMP(W2_, c_) : (vi_) == 3 ? CMP(W3_, c_) : \
     (vi_) == 4 ? CMP(W4_, c_) : CMP(W5_, c_))

#define WSTORE(vi_, e_) do {                                              \
    if      ((vi_) == 0) W0_ = (e_); else if ((vi_) == 1) W1_ = (e_);     \
    else if ((vi_) == 2) W2_ = (e_); else if ((vi_) == 3) W3_ = (e_);     \
    else if ((vi_) == 4) W4_ = (e_); else                 W5_ = (e_);     \
    } while (0)

    // round with round-index R_ (mask/parity) and rotation phase K_ (=R_ mod 6
    // folded statically); MASKED_=1 enables the ragged-term prune.
#define ROUND_BODY(K_, R_, MASKED_)                                       \
    {                                                                     \
        const float4 xc = ((R_) & 1) ? xb_ : xa_;                         \
        _Pragma("unroll")                                                 \
        for (int d = 0; d < 4; ++d) {                                     \
            const float xv = CMP(xc, d);                                  \
            _Pragma("unroll")                                             \
            for (int j = 0; j < J; ++j) {                                 \
                if (!(MASKED_) || (8 * (R_) + 2 * d < N0 + j)) {          \
                    const int g  = KOFF + j - d;                          \
                    const int vi = ((Q0 + g / 4 - (K_)) % 6 + 6) % 6;     \
                    acc[j] = fmaf(xv, WREAD(vi, g & 3), acc[j]);          \
                }                                                         \
            }                                                             \
        }                                                                 \
    }

    // ---- init: quads Q0..Q0+5 into vars (Q0+i)%6 (clip quads>39), x quad 0
    #pragma unroll
    for (int i = 0; i < 6; ++i) {
        const float4 q = (Q0 + i <= 39) ? col4[(Q0 + i) * 64]
                                        : make_float4(0.f, 0.f, 0.f, 0.f);
        WSTORE((Q0 + i) % 6, q);
    }
    xa_ = col4[0];

    // ---- runtime x6 trips: rounds r = 6t+k, all clean ----
    const float4* xq = col4;                 // x base: quad 6t
    const float4* wq = col4 + Q0 * 64;       // refill base: quad Q0-6t
    #pragma unroll 1
    for (int t = 0; t < T; ++t) {
        #pragma unroll
        for (int k = 0; k < 6; ++k) {
            if (((k + 1) & 1) == 0) xa_ = xq[(k + 1) * 64];
            else                    xb_ = xq[(k + 1) * 64];
            ROUND_BODY(k, k, 0)
            // refill quad Q0-6t-k-1 -> var just freed this round
            WSTORE(((Q0 - k - 1) % 6 + 6) % 6, wq[-(k + 1) * 64]);
        }
        xq += 6 * 64;
        wq -= 6 * 64;
    }

    // ---- static rounds rr = R6..RT-1 (clean remainder + ragged) ----
    #pragma unroll
    for (int u = 0; u < RT - R6; ++u) {
        const int rr = R6 + u;                       // constant after unroll
        if (rr + 1 < RT) {                           // compile-time guard
            if (((rr + 1) & 1) == 0) xa_ = col4[(rr + 1) * 64];
            else                     xb_ = col4[(rr + 1) * 64];
        }
        ROUND_BODY(rr, rr, (rr >= RC))
        if (rr + 1 < RT)
            WSTORE(((Q0 - rr - 1) % 6 + 6) % 6, col4[(Q0 - rr - 1) * 64]);
    }

    // ---- finalize: x2 + center term for even lags, local argmax ----
    #pragma unroll
    for (int j = 0; j < J; ++j) {
        float v2 = acc[j] + acc[j];
        if ((N0 + j) % 2 == 0) {
            const int R = (N0 + j) / 2;              // constant after unroll
            const float c = colf[(R / 4) * 256 + (R & 3)];
            v2 = fmaf(c, c, v2);
        }
        if (v2 > best) { best = v2; bl = N0 + j; }   // strict >: first max
    }
#undef ROUND_BODY
#undef WSTORE
#undef WREAD
}

// One 64-frame pass: mean -> center -> LDS -> conv tiles -> argmax -> out.
// a[10] arrives as staged (possibly still in-flight) global loads; the
// first read of a[] here is where the compiler places the vmcnt wait.
__device__ __forceinline__ void pass_body(float4 (&a)[10],
                                          float4* __restrict__ X4,
                                          float* __restrict__ Xa,
                                          const int s, const int f,
                                          float* __restrict__ outp) {
    // ---- mean via aux rows (waits on this pass's loads) ----
    float ps = 0.f;
    #pragma unroll
    for (int j = 0; j < 10; ++j) ps += a[j].x + a[j].y + a[j].z + a[j].w;
    Xa[s * 64 + f] = ps;
    __syncthreads();
    const float mu = (Xa[f] + Xa[64 + f] + Xa[128 + f] + Xa[192 + f]) * (1.0f / 160.0f);

    // center in place; pm = max|c| via fmax(c,-c) (v_max3 w/ neg modifier)
    float pm = 0.f;
    #pragma unroll
    for (int j = 0; j < 10; ++j) {
        a[j].x -= mu; a[j].y -= mu; a[j].z -= mu; a[j].w -= mu;
        pm = fmaxf(pm, fmaxf(fmaxf(a[j].x, -a[j].x), fmaxf(a[j].y, -a[j].y)));
        pm = fmaxf(pm, fmaxf(fmaxf(a[j].z, -a[j].z), fmaxf(a[j].w, -a[j].w)));
    }
    __syncthreads();                       // sum-reads done before overwrite

    // ---- write centered frames as row-quads (b128, contiguous) ----
    #pragma unroll
    for (int k = 0; k < 10; ++k)
        X4[(10 * s + k) * 64 + f] = a[k];
    __syncthreads();

    // ---- paired balanced tiles (rounds 27/27/28/28) ----
    const float4* col4 = X4 + f;
    const float*  colf = Xa + 4 * f;
    float best = -3.4e38f; int bl = 0;
    if      (s == 0) { conv_tile< 40>(col4, colf, best, bl);
                       conv_tile<145>(col4, colf, best, bl); }
    else if (s == 1) { conv_tile< 55>(col4, colf, best, bl);
                       conv_tile<130>(col4, colf, best, bl); }
    else if (s == 2) { conv_tile< 70>(col4, colf, best, bl);
                       conv_tile<115>(col4, colf, best, bl); }
    else             { conv_tile< 85>(col4, colf, best, bl);
                       conv_tile<100>(col4, colf, best, bl); }
    __syncthreads();                       // conv done: X now dead

    // ---- cross-wave argmax + silent-check via aux rows ----
    Xa[s * 64 + f] = best;
    reinterpret_cast<int*>(Xa)[256 + s * 64 + f] = bl;
    Xa[512 + s * 64 + f] = pm;
    __syncthreads();

    if (s == 0) {
        float bv = Xa[f];
        int   L  = reinterpret_cast<int*>(Xa)[256 + f];
        #pragma unroll
        for (int c = 1; c < 4; ++c) {
            const float vv = Xa[c * 64 + f];
            const int   lv = reinterpret_cast<int*>(Xa)[256 + c * 64 + f];
            if (vv > bv || (vv == bv && lv < L)) { bv = vv; L = lv; }
        }
        const float mx = fmaxf(fmaxf(Xa[512 + f], Xa[512 + 64 + f]),
                               fmaxf(Xa[512 + 128 + f], Xa[512 + 192 + f]));
        const float pitch = SR_F / (float)L;
        outp[f] = (mx < 1e-8f) ? 0.0f : pitch;
    }
    __syncthreads();                       // reduce reads done before next pass
}

__global__ __launch_bounds__(256)
void pitch_kernel(const float* __restrict__ audio, float* __restrict__ out) {
    __shared__ float4 X4[40 * 64];                   // 40960 B
    float* Xa = reinterpret_cast<float*>(X4);

    const int tid = threadIdx.x;
    const int s   = tid >> 6;          // wave id (sample chunk)
    const int f   = tid & 63;          // frame within set
    const int blk = blockIdx.x;
    const int b   = blk >> 5;          // batch row (32 blocks per batch)
    const int t0  = (blk & 31) << 7;   // first frame of block (128 frames)

    // ---- Issue ALL global loads up-front: pass-0 (a0) then pass-1 (a1).
    // a0 is waited at pass-0's mean; a1 stays in flight through pass-0's
    // whole conv (~3us VALU issue) and is waited at pass-1's mean.
    const float* g0 = audio + (size_t)b * SAMPLES + (size_t)(t0 + f) * HOPSZ + s * 40;
    const float* g1 = g0 + 64 * HOPSZ;

    float4 a0[10], a1[10];
    #pragma unroll
    for (int j = 0; j < 10; ++j) a0[j] = reinterpret_cast<const float4*>(g0)[j];
    #pragma unroll
    for (int j = 0; j < 10; ++j) a1[j] = reinterpret_cast<const float4*>(g1)[j];
    __builtin_amdgcn_sched_barrier(0);   // pin load issue above everything

    pass_body(a0, X4, Xa, s, f, out + (size_t)b * TFRAMES + t0);
    pass_body(a1, X4, Xa, s, f, out + (size_t)b * TFRAMES + t0 + 64);
}

extern "C" void kernel_launch(void* const* d_in, const int* in_sizes, int n_in,
                              void* d_out, int out_size, void* d_ws, size_t ws_size,
                              hipStream_t stream) {
    const float* audio = (const float*)d_in[0];
    float* out = (float*)d_out;
    pitch_kernel<<<dim3(512), dim3(256), 0, stream>>>(audio, out);
}

// Round 3
// 96.155 us; speedup vs baseline: 1.0807x; 1.0807x over previous
//
#include <hip/hip_runtime.h>

// SimplePitchEstimator on MI355X (gfx950).
// ac = irfft(rfft(x,512)^2) == linear self-convolution c[n] = sum y[i]y[n-i],
// y = x - mean(x). Round-15: r12 structure + packed-FP32 conv (v_pk_fma_f32).
//
// Evidence chain: r12 = 97.17us = 2x ~42.5us harness poison fills
// (immutable) + ~12.1us kernel (~6.7us HBM + ~5.5us VALU, serial).
// r13 cross-block s_sleep stagger: +3.9us (= sleep offset, zero overlap
// -> dispatch-mapping games refuted). r14 2-pass pipeline: +6.7us
// (oversubscribed HBM completes per-wave loads ~at drain time regardless
// of issue order; 2 blocks/CU starves issue; 40 live VGPRs across
// unrolled conv risks r9-style spill). Conclusion: overlap is not
// purchasable here; optimize WITHIN the serial structure.
// This round: cut the VALU term with gfx90a+ full-rate packed FP32.
// Window kept as 12 named f32x2 vars (same 24 VGPRs as 6 float4s) so
// lag-pairs (j,j+1) with even g = KOFF+j-d are register-native aligned
// pairs; __builtin_elementwise_fma(f32x2) -> v_pk_fma_f32. Per clean
// round: 2 of 4 d's (compile-time parity) pack to 7 pk_fma + 1 fma,
// other 2 d's stay scalar: 46 vs 60 issue slots (-23%). Same fma ops,
// same order -> bit-identical. Masked rounds stay scalar.
// Predicted kernel ~10.8-11.2us, dur 97.17 -> 95.5-96.5 (neutral ~97.2
// if pk selection declines; fallback is op-identical scalar).
//
//  * Twelve NAMED f32x2 vars P0..P11 hold the 6 window quads as aligned
//    halves; quad->var map (quad % 6) repeats every 6 rounds; every
//    reference is a static component/pair of a named var (no array).
//  * Refill ds_read_b128 -> two f32x2 splits into the rotating target
//    vars, placed after the round's FMAs; x quads via 2-var ping-pong.
//  * Remainder + ragged rounds statically unrolled, affine masks
//    8r+2d < N0+j.
//  * Half-sum c[n] = 2*sum_{2i<n} y_i y_{n-i} + center (validated r6-r10).
//  * LDS 160x64x4 = 40960 B exactly (4 blocks/CU, 1024 blocks co-resident);
//    balanced tile pairs 27/27/28/28; mu folded at LDS write; silent-check
//    pm rides in a register to the final reduction.

#define SR_F    16000.0f
#define HOPSZ   256
#define TFRAMES 4096
#define SAMPLES 1048576

typedef __attribute__((ext_vector_type(2))) float f32x2;

#define CMP(v_, c_) ((c_) == 0 ? (v_).x : (c_) == 1 ? (v_).y : \
                     (c_) == 2 ? (v_).z : (v_).w)

template<int N0>
__device__ __forceinline__ void conv_tile(const float4* __restrict__ col4,
                                          const float* __restrict__ colf,
                                          float& best, int& bl) {
    constexpr int J    = 15;
    constexpr int B0   = ((N0 - 3) / 4) * 4;   // aligned window base row
    constexpr int Q0   = B0 / 4;               // base quad at round 0
    constexpr int KOFF = N0 - B0;              // 3..6
    constexpr int IC   = (N0 + J) / 2;         // i-count for max lag
    constexpr int RT   = (IC + 3) / 4;         // total rounds
    constexpr int RC   = (N0 - 6 + 7) / 8;     // clean rounds (8r+6 < N0)
    constexpr int T    = RC / 6;               // runtime x6 trips
    constexpr int R6   = 6 * T;                // first static round
    static_assert(KOFF >= 3 && KOFF + J - 1 <= 20, "window index bound");
    static_assert(RC >= 1 && RC <= RT - 1, "clean/ragged split");
    static_assert(Q0 - RT + 1 >= 0, "refill quad in range");

    // acc: 7 packed lag-pairs + scalar j=14. accJ(j) maps identically to
    // the old acc[j]; all fma ops/order unchanged -> bit-identical.
    f32x2 acc2[7];
    float acc14 = 0.f;
    #pragma unroll
    for (int p = 0; p < 7; ++p) acc2[p] = f32x2{0.f, 0.f};

    // window: quad-var vi (0..5) -> pair vars (2vi, 2vi+1)
    f32x2 P0_, P1_, P2_, P3_, P4_, P5_, P6_, P7_, P8_, P9_, P10_, P11_;
    float4 xa_, xb_;

#define PPAIR(pi_) \
    ((pi_) == 0 ? P0_ : (pi_) == 1 ? P1_ : (pi_) == 2 ? P2_ :  \
     (pi_) == 3 ? P3_ : (pi_) == 4 ? P4_ : (pi_) == 5 ? P5_ :  \
     (pi_) == 6 ? P6_ : (pi_) == 7 ? P7_ : (pi_) == 8 ? P8_ :  \
     (pi_) == 9 ? P9_ : (pi_) == 10 ? P10_ : P11_)

#define PREAD(pi_, h_) ((h_) ? PPAIR(pi_).y : PPAIR(pi_).x)

#define PST(pi_, e_) do {                                                 \
    if      ((pi_) == 0)  P0_  = (e_); else if ((pi_) == 1)  P1_  = (e_); \
    else if ((pi_) == 2)  P2_  = (e_); else if ((pi_) == 3)  P3_  = (e_); \
    else if ((pi_) == 4)  P4_  = (e_); else if ((pi_) == 5)  P5_  = (e_); \
    else if ((pi_) == 6)  P6_  = (e_); else if ((pi_) == 7)  P7_  = (e_); \
    else if ((pi_) == 8)  P8_  = (e_); else if ((pi_) == 9)  P9_  = (e_); \
    else if ((pi_) == 10) P10_ = (e_); else                  P11_ = (e_); \
    } while (0)

#define WSTORE(vi_, q_) do {                                              \
    PST(2 * (vi_),     (f32x2{(q_).x, (q_).y}));                          \
    PST(2 * (vi_) + 1, (f32x2{(q_).z, (q_).w}));                          \
    } while (0)

    // round with round-index R_ (mask/parity) and rotation phase K_ (=R_ mod 6
    // folded statically); MASKED_=1 enables the ragged-term prune (scalar).
    // Clean rounds: d with (KOFF-d) even -> lag-pairs (2p,2p+1) hit even
    // g = KOFF+2p-d -> aligned pair var -> one v_pk_fma_f32.
#define ROUND_BODY(K_, R_, MASKED_)                                       \
    {                                                                     \
        const float4 xc = ((R_) & 1) ? xb_ : xa_;                         \
        _Pragma("unroll")                                                 \
        for (int d = 0; d < 4; ++d) {                                     \
            const float xv = CMP(xc, d);                                  \
            if (!(MASKED_) && (((KOFF - d) & 1) == 0)) {                  \
                const f32x2 xv2 = {xv, xv};                               \
                _Pragma("unroll")                                         \
                for (int p = 0; p < 7; ++p) {                             \
                    const int g  = KOFF + 2 * p - d;       /* even */     \
                    const int vi = ((Q0 + g / 4 - (K_)) % 6 + 6) % 6;     \
                    const int pi = 2 * vi + ((g >> 1) & 1);               \
                    acc2[p] = __builtin_elementwise_fma(xv2, PPAIR(pi),   \
                                                        acc2[p]);         \
                }                                                         \
                {                                                         \
                    const int g  = KOFF + 14 - d;                         \
                    const int vi = ((Q0 + g / 4 - (K_)) % 6 + 6) % 6;     \
                    const int pi = 2 * vi + ((g >> 1) & 1);               \
                    acc14 = fmaf(xv, PREAD(pi, g & 1), acc14);            \
                }                                                         \
            } else {                                                      \
                _Pragma("unroll")                                         \
                for (int j = 0; j < J; ++j) {                             \
                    if (!(MASKED_) || (8 * (R_) + 2 * d < N0 + j)) {      \
                        const int g  = KOFF + j - d;                      \
                        const int vi = ((Q0 + g / 4 - (K_)) % 6 + 6) % 6; \
                        const int pi = 2 * vi + ((g >> 1) & 1);           \
                        const float wv = PREAD(pi, g & 1);                \
                        if (j == 14)                                      \
                            acc14 = fmaf(xv, wv, acc14);                  \
                        else if (j & 1)                                   \
                            acc2[j >> 1].y = fmaf(xv, wv, acc2[j >> 1].y);\
                        else                                              \
                            acc2[j >> 1].x = fmaf(xv, wv, acc2[j >> 1].x);\
                    }                                                     \
                }                                                         \
            }                                                             \
        }                                                                 \
    }

    // ---- init: quads Q0..Q0+5 into vars (Q0+i)%6 (clip quads>39), x quad 0
    #pragma unroll
    for (int i = 0; i < 6; ++i) {
        const float4 q = (Q0 + i <= 39) ? col4[(Q0 + i) * 64]
                                        : make_float4(0.f, 0.f, 0.f, 0.f);
        WSTORE((Q0 + i) % 6, q);
    }
    xa_ = col4[0];

    // ---- runtime x6 trips: rounds r = 6t+k, all clean ----
    const float4* xq = col4;                 // x base: quad 6t
    const float4* wq = col4 + Q0 * 64;       // refill base: quad Q0-6t
    #pragma unroll 1
    for (int t = 0; t < T; ++t) {
        #pragma unroll
        for (int k = 0; k < 6; ++k) {
            if (((k + 1) & 1) == 0) xa_ = xq[(k + 1) * 64];
            else                    xb_ = xq[(k + 1) * 64];
            ROUND_BODY(k, k, 0)
            // refill quad Q0-6t-k-1 -> var just freed this round
            {
                const float4 rq = wq[-(k + 1) * 64];
                WSTORE(((Q0 - k - 1) % 6 + 6) % 6, rq);
            }
        }
        xq += 6 * 64;
        wq -= 6 * 64;
    }

    // ---- static rounds rr = R6..RT-1 (clean remainder + ragged) ----
    #pragma unroll
    for (int u = 0; u < RT - R6; ++u) {
        const int rr = R6 + u;                       // constant after unroll
        if (rr + 1 < RT) {                           // compile-time guard
            if (((rr + 1) & 1) == 0) xa_ = col4[(rr + 1) * 64];
            else                     xb_ = col4[(rr + 1) * 64];
        }
        ROUND_BODY(rr, rr, (rr >= RC))
        if (rr + 1 < RT) {
            const float4 rq = col4[(Q0 - rr - 1) * 64];
            WSTORE(((Q0 - rr - 1) % 6 + 6) % 6, rq);
        }
    }

    // ---- finalize: x2 + center term for even lags, local argmax ----
    #pragma unroll
    for (int j = 0; j < J; ++j) {
        const float aj = (j == 14) ? acc14
                        : ((j & 1) ? acc2[j >> 1].y : acc2[j >> 1].x);
        float v2 = aj + aj;
        if ((N0 + j) % 2 == 0) {
            const int R = (N0 + j) / 2;              // constant after unroll
            const float c = colf[(R / 4) * 256 + (R & 3)];
            v2 = fmaf(c, c, v2);
        }
        if (v2 > best) { best = v2; bl = N0 + j; }   // strict >: first max
    }
#undef ROUND_BODY
#undef WSTORE
#undef PST
#undef PREAD
#undef PPAIR
}

__global__ __launch_bounds__(256)
void pitch_kernel(const float* __restrict__ audio, float* __restrict__ out) {
    __shared__ float4 X4[40 * 64];                   // 40960 B exactly
    float* Xa = reinterpret_cast<float*>(X4);

    const int tid = threadIdx.x;
    const int s   = tid >> 6;          // wave id
    const int f   = tid & 63;          // frame within block
    const int blk = blockIdx.x;
    const int b   = blk >> 6;          // batch row
    const int t0  = (blk & 63) << 6;   // first frame of block

    // ---- Phase A: load 40 samples of frame f (chunk s), partial sum ----
    const float* g = audio + (size_t)b * SAMPLES + (size_t)(t0 + f) * HOPSZ + s * 40;
    float v[40];
    float ps = 0.f;
    #pragma unroll
    for (int j = 0; j < 10; ++j) {
        float4 q = reinterpret_cast<const float4*>(g)[j];   // 16B-aligned
        v[4*j+0] = q.x; v[4*j+1] = q.y; v[4*j+2] = q.z; v[4*j+3] = q.w;
        ps += q.x + q.y + q.z + q.w;
    }

    // ---- Phase B: block mean via aux rows; pm stays in a register ----
    Xa[s * 64 + f] = ps;
    __syncthreads();
    const float mu = (Xa[f] + Xa[64 + f] + Xa[128 + f] + Xa[192 + f]) * (1.0f / 160.0f);
    // center in place; pm = max|c| via fmax(c,-c) (v_max3 w/ neg modifier)
    #pragma unroll
    for (int q = 0; q < 40; ++q) v[q] = v[q] - mu;
    float pm = 0.f;
    #pragma unroll
    for (int q = 0; q < 40; ++q) pm = fmaxf(pm, fmaxf(v[q], -v[q]));
    __syncthreads();                       // sum-reads done before D overwrites

    // ---- Phase D: write centered frames as row-quads (b128, contiguous) ----
    #pragma unroll
    for (int k = 0; k < 10; ++k)
        X4[(10 * k + k * 0 + 10 * s + k * 0) * 0 + (10 * s + k) * 64 + f] =
            make_float4(v[4*k+0], v[4*k+1], v[4*k+2], v[4*k+3]);
    __syncthreads();

    // ---- Phase E: paired balanced tiles (rounds 27/27/28/28) ----
    const float4* col4 = X4 + f;
    const float*  colf = Xa + 4 * f;
    float best = -3.4e38f; int bl = 0;
    if      (s == 0) { conv_tile< 40>(col4, colf, best, bl);
                       conv_tile<145>(col4, colf, best, bl); }
    else if (s == 1) { conv_tile< 55>(col4, colf, best, bl);
                       conv_tile<130>(col4, colf, best, bl); }
    else if (s == 2) { conv_tile< 70>(col4, colf, best, bl);
                       conv_tile<115>(col4, colf, best, bl); }
    else             { conv_tile< 85>(col4, colf, best, bl);
                       conv_tile<100>(col4, colf, best, bl); }
    __syncthreads();                       // conv done: X now dead

    // ---- Phase F: cross-wave argmax + silent-check via aux rows ----
    Xa[s * 64 + f] = best;
    reinterpret_cast<int*>(Xa)[256 + s * 64 + f] = bl;
    Xa[512 + s * 64 + f] = pm;
    __syncthreads();

    if (s == 0) {
        float bv = Xa[f];
        int   L  = reinterpret_cast<int*>(Xa)[256 + f];
        #pragma unroll
        for (int c = 1; c < 4; ++c) {
            const float vv = Xa[c * 64 + f];
            const int   lv = reinterpret_cast<int*>(Xa)[256 + c * 64 + f];
            if (vv > bv || (vv == bv && lv < L)) { bv = vv; L = lv; }
        }
        const float mx = fmaxf(fmaxf(Xa[512 + f], Xa[512 + 64 + f]),
                               fmaxf(Xa[512 + 128 + f], Xa[512 + 192 + f]));
        const float pitch = SR_F / (float)L;
        out[(size_t)b * TFRAMES + t0 + f] = (mx < 1e-8f) ? 0.0f : pitch;
    }
}

extern "C" void kernel_launch(void* const* d_in, const int* in_sizes, int n_in,
                              void* d_out, int out_size, void* d_ws, size_t ws_size,
                              hipStream_t stream) {
    const float* audio = (const float*)d_in[0];
    float* out = (float*)d_out;
    pitch_kernel<<<dim3(1024), dim3(256), 0, stream>>>(audio, out);
}

// Round 4
// 95.538 us; speedup vs baseline: 1.0877x; 1.0065x over previous
//
#include <hip/hip_runtime.h>

// SimplePitchEstimator on MI355X (gfx950).
// ac = irfft(rfft(x,512)^2) == linear self-convolution c[n] = sum y[i]y[n-i],
// y = x - mean(x). Round-16: full packed-FP32 conv via dual accumulator banks.
//
// Evidence chain: r12 = 97.17us = 2x ~42.5us harness poison fills
// (immutable) + ~12.1us kernel (~6.7us HBM + ~5.5us VALU, serial; overlap
// empirically unpurchasable: r13 s_sleep stagger +3.9us, r14 2-pass
// pipeline +6.7us). r15 packed the even-parity half of each round
// (60 -> 46 issue slots) -> 96.15us, matching prediction; v_pk_fma_f32
// confirmed live. This round packs the odd-parity d's too: bank-B
// accumulators with shifted pairing (1,2),(3,4),...,(13,14)+scalar j0,
// so pair base j=2p+1 gives even g -> aligned window pair -> pk_fma.
// Clean round: 4 x (7 pk + 1 fma) = 32 slots (vs 46/60). Finalize sums
// A[j]+B[j] (regroups the sum by d-parity; ~ulp perturbation, argmax
// already tolerant of direct-vs-FFT divergence at absmax 0.0).
// +16 VGPR (bank B) ~= 110 total, below the 128 cliff (LDS-pinned
// 4 blocks/CU = 4 waves/SIMD preserved).
// Predicted kernel ~10us, dur 96.15 -> 94.8-95.5; revert bank B if >=98.

#define SR_F    16000.0f
#define HOPSZ   256
#define TFRAMES 4096
#define SAMPLES 1048576

typedef __attribute__((ext_vector_type(2))) float f32x2;

#define CMP(v_, c_) ((c_) == 0 ? (v_).x : (c_) == 1 ? (v_).y : \
                     (c_) == 2 ? (v_).z : (v_).w)

template<int N0>
__device__ __forceinline__ void conv_tile(const float4* __restrict__ col4,
                                          const float* __restrict__ colf,
                                          float& best, int& bl) {
    constexpr int J    = 15;
    constexpr int B0   = ((N0 - 3) / 4) * 4;   // aligned window base row
    constexpr int Q0   = B0 / 4;               // base quad at round 0
    constexpr int KOFF = N0 - B0;              // 3..6
    constexpr int IC   = (N0 + J) / 2;         // i-count for max lag
    constexpr int RT   = (IC + 3) / 4;         // total rounds
    constexpr int RC   = (N0 - 6 + 7) / 8;     // clean rounds (8r+6 < N0)
    constexpr int T    = RC / 6;               // runtime x6 trips
    constexpr int R6   = 6 * T;                // first static round
    static_assert(KOFF >= 3 && KOFF + J - 1 <= 20, "window index bound");
    static_assert(RC >= 1 && RC <= RT - 1, "clean/ragged split");
    static_assert(Q0 - RT + 1 >= 0, "refill quad in range");

    // Bank A: pairs (0,1)(2,3)...(12,13) + scalar j=14  (even-parity d's)
    // Bank B: pairs (1,2)(3,4)...(13,14) + scalar j=0   (odd-parity d's)
    // final acc[j] = A[j] + B[j]; regrouping by d-parity only.
    f32x2 accA[7], accB[7];
    float accA14 = 0.f, accB0 = 0.f;
    #pragma unroll
    for (int p = 0; p < 7; ++p) { accA[p] = f32x2{0.f, 0.f};
                                  accB[p] = f32x2{0.f, 0.f}; }

    // window: quad-var vi (0..5) -> pair vars (2vi, 2vi+1)
    f32x2 P0_, P1_, P2_, P3_, P4_, P5_, P6_, P7_, P8_, P9_, P10_, P11_;
    float4 xa_, xb_;

#define PPAIR(pi_) \
    ((pi_) == 0 ? P0_ : (pi_) == 1 ? P1_ : (pi_) == 2 ? P2_ :  \
     (pi_) == 3 ? P3_ : (pi_) == 4 ? P4_ : (pi_) == 5 ? P5_ :  \
     (pi_) == 6 ? P6_ : (pi_) == 7 ? P7_ : (pi_) == 8 ? P8_ :  \
     (pi_) == 9 ? P9_ : (pi_) == 10 ? P10_ : P11_)

#define PREAD(pi_, h_) ((h_) ? PPAIR(pi_).y : PPAIR(pi_).x)

#define PST(pi_, e_) do {                                                 \
    if      ((pi_) == 0)  P0_  = (e_); else if ((pi_) == 1)  P1_  = (e_); \
    else if ((pi_) == 2)  P2_  = (e_); else if ((pi_) == 3)  P3_  = (e_); \
    else if ((pi_) == 4)  P4_  = (e_); else if ((pi_) == 5)  P5_  = (e_); \
    else if ((pi_) == 6)  P6_  = (e_); else if ((pi_) == 7)  P7_  = (e_); \
    else if ((pi_) == 8)  P8_  = (e_); else if ((pi_) == 9)  P9_  = (e_); \
    else if ((pi_) == 10) P10_ = (e_); else                  P11_ = (e_); \
    } while (0)

#define WSTORE(vi_, q_) do {                                              \
    PST(2 * (vi_),     (f32x2{(q_).x, (q_).y}));                          \
    PST(2 * (vi_) + 1, (f32x2{(q_).z, (q_).w}));                          \
    } while (0)

    // round with round-index R_ (mask/parity) and rotation phase K_ (=R_ mod 6
    // folded statically); MASKED_=1 -> ragged prune, all-scalar into bank A.
    // Clean rounds: even-parity d -> bank A pairs (g = KOFF+2p-d even);
    //               odd-parity d  -> bank B pairs (g = KOFF+2p+1-d even).
#define ROUND_BODY(K_, R_, MASKED_)                                       \
    {                                                                     \
        const float4 xc = ((R_) & 1) ? xb_ : xa_;                         \
        _Pragma("unroll")                                                 \
        for (int d = 0; d < 4; ++d) {                                     \
            const float xv = CMP(xc, d);                                  \
            if (!(MASKED_) && (((KOFF - d) & 1) == 0)) {                  \
                const f32x2 xv2 = {xv, xv};                               \
                _Pragma("unroll")                                         \
                for (int p = 0; p < 7; ++p) {                             \
                    const int g  = KOFF + 2 * p - d;       /* even */     \
                    const int vi = ((Q0 + g / 4 - (K_)) % 6 + 6) % 6;     \
                    const int pi = 2 * vi + ((g >> 1) & 1);               \
                    accA[p] = __builtin_elementwise_fma(xv2, PPAIR(pi),   \
                                                        accA[p]);         \
                }                                                         \
                {                                                         \
                    const int g  = KOFF + 14 - d;                         \
                    const int vi = ((Q0 + g / 4 - (K_)) % 6 + 6) % 6;     \
                    const int pi = 2 * vi + ((g >> 1) & 1);               \
                    accA14 = fmaf(xv, PREAD(pi, g & 1), accA14);          \
                }                                                         \
            } else if (!(MASKED_)) {                                      \
                const f32x2 xv2 = {xv, xv};                               \
                {                                                         \
                    const int g  = KOFF + 0 - d;           /* even */     \
                    const int vi = ((Q0 + g / 4 - (K_)) % 6 + 6) % 6;     \
                    const int pi = 2 * vi + ((g >> 1) & 1);               \
                    accB0 = fmaf(xv, PREAD(pi, g & 1), accB0);            \
                }                                                         \
                _Pragma("unroll")                                         \
                for (int p = 0; p < 7; ++p) {                             \
                    const int g  = KOFF + 2 * p + 1 - d;   /* even */     \
                    const int vi = ((Q0 + g / 4 - (K_)) % 6 + 6) % 6;     \
                    const int pi = 2 * vi + ((g >> 1) & 1);               \
                    accB[p] = __builtin_elementwise_fma(xv2, PPAIR(pi),   \
                                                        accB[p]);         \
                }                                                         \
            } else {                                                      \
                _Pragma("unroll")                                         \
                for (int j = 0; j < J; ++j) {                             \
                    if (8 * (R_) + 2 * d < N0 + j) {                      \
                        const int g  = KOFF + j - d;                      \
                        const int vi = ((Q0 + g / 4 - (K_)) % 6 + 6) % 6; \
                        const int pi = 2 * vi + ((g >> 1) & 1);           \
                        const float wv = PREAD(pi, g & 1);                \
                        if (j == 14)                                      \
                            accA14 = fmaf(xv, wv, accA14);                \
                        else if (j & 1)                                   \
                            accA[j >> 1].y = fmaf(xv, wv, accA[j >> 1].y);\
                        else                                              \
                            accA[j >> 1].x = fmaf(xv, wv, accA[j >> 1].x);\
                    }                                                     \
                }                                                         \
            }                                                             \
        }                                                                 \
    }

    // ---- init: quads Q0..Q0+5 into vars (Q0+i)%6 (clip quads>39), x quad 0
    #pragma unroll
    for (int i = 0; i < 6; ++i) {
        const float4 q = (Q0 + i <= 39) ? col4[(Q0 + i) * 64]
                                        : make_float4(0.f, 0.f, 0.f, 0.f);
        WSTORE((Q0 + i) % 6, q);
    }
    xa_ = col4[0];

    // ---- runtime x6 trips: rounds r = 6t+k, all clean ----
    const float4* xq = col4;                 // x base: quad 6t
    const float4* wq = col4 + Q0 * 64;       // refill base: quad Q0-6t
    #pragma unroll 1
    for (int t = 0; t < T; ++t) {
        #pragma unroll
        for (int k = 0; k < 6; ++k) {
            if (((k + 1) & 1) == 0) xa_ = xq[(k + 1) * 64];
            else                    xb_ = xq[(k + 1) * 64];
            ROUND_BODY(k, k, 0)
            // refill quad Q0-6t-k-1 -> var just freed this round
            {
                const float4 rq = wq[-(k + 1) * 64];
                WSTORE(((Q0 - k - 1) % 6 + 6) % 6, rq);
            }
        }
        xq += 6 * 64;
        wq -= 6 * 64;
    }

    // ---- static rounds rr = R6..RT-1 (clean remainder + ragged) ----
    #pragma unroll
    for (int u = 0; u < RT - R6; ++u) {
        const int rr = R6 + u;                       // constant after unroll
        if (rr + 1 < RT) {                           // compile-time guard
            if (((rr + 1) & 1) == 0) xa_ = col4[(rr + 1) * 64];
            else                     xb_ = col4[(rr + 1) * 64];
        }
        ROUND_BODY(rr, rr, (rr >= RC))
        if (rr + 1 < RT) {
            const float4 rq = col4[(Q0 - rr - 1) * 64];
            WSTORE(((Q0 - rr - 1) % 6 + 6) % 6, rq);
        }
    }

    // ---- finalize: combine banks, x2 + center term, local argmax ----
    // A[j]: j=14 -> accA14; else lane (j&1) of accA[j>>1].
    // B[j]: j=0 -> accB0; j odd -> accB[(j-1)/2].x; j even -> accB[j/2-1].y.
    #pragma unroll
    for (int j = 0; j < J; ++j) {
        const float av = (j == 14) ? accA14
                        : ((j & 1) ? accA[j >> 1].y : accA[j >> 1].x);
        const float bv2 = (j == 0) ? accB0
                        : ((j & 1) ? accB[(j - 1) >> 1].x : accB[j / 2 - 1].y);
        const float aj = av + bv2;
        float v2 = aj + aj;
        if ((N0 + j) % 2 == 0) {
            const int R = (N0 + j) / 2;              // constant after unroll
            const float c = colf[(R / 4) * 256 + (R & 3)];
            v2 = fmaf(c, c, v2);
        }
        if (v2 > best) { best = v2; bl = N0 + j; }   // strict >: first max
    }
#undef ROUND_BODY
#undef WSTORE
#undef PST
#undef PREAD
#undef PPAIR
}

__global__ __launch_bounds__(256)
void pitch_kernel(const float* __restrict__ audio, float* __restrict__ out) {
    __shared__ float4 X4[40 * 64];                   // 40960 B exactly
    float* Xa = reinterpret_cast<float*>(X4);

    const int tid = threadIdx.x;
    const int s   = tid >> 6;          // wave id
    const int f   = tid & 63;          // frame within block
    const int blk = blockIdx.x;
    const int b   = blk >> 6;          // batch row
    const int t0  = (blk & 63) << 6;   // first frame of block

    // ---- Phase A: load 40 samples of frame f (chunk s), partial sum ----
    const float* g = audio + (size_t)b * SAMPLES + (size_t)(t0 + f) * HOPSZ + s * 40;
    float v[40];
    float ps = 0.f;
    #pragma unroll
    for (int j = 0; j < 10; ++j) {
        float4 q = reinterpret_cast<const float4*>(g)[j];   // 16B-aligned
        v[4*j+0] = q.x; v[4*j+1] = q.y; v[4*j+2] = q.z; v[4*j+3] = q.w;
        ps += q.x + q.y + q.z + q.w;
    }

    // ---- Phase B: block mean via aux rows; pm stays in a register ----
    Xa[s * 64 + f] = ps;
    __syncthreads();
    const float mu = (Xa[f] + Xa[64 + f] + Xa[128 + f] + Xa[192 + f]) * (1.0f / 160.0f);
    // center in place; pm = max|c| via fmax(c,-c) (v_max3 w/ neg modifier)
    #pragma unroll
    for (int q = 0; q < 40; ++q) v[q] = v[q] - mu;
    float pm = 0.f;
    #pragma unroll
    for (int q = 0; q < 40; ++q) pm = fmaxf(pm, fmaxf(v[q], -v[q]));
    __syncthreads();                       // sum-reads done before D overwrites

    // ---- Phase D: write centered frames as row-quads (b128, contiguous) ----
    #pragma unroll
    for (int k = 0; k < 10; ++k)
        X4[(10 * s + k) * 64 + f] =
            make_float4(v[4*k+0], v[4*k+1], v[4*k+2], v[4*k+3]);
    __syncthreads();

    // ---- Phase E: paired balanced tiles (rounds 27/27/28/28) ----
    const float4* col4 = X4 + f;
    const float*  colf = Xa + 4 * f;
    float best = -3.4e38f; int bl = 0;
    if      (s == 0) { conv_tile< 40>(col4, colf, best, bl);
                       conv_tile<145>(col4, colf, best, bl); }
    else if (s == 1) { conv_tile< 55>(col4, colf, best, bl);
                       conv_tile<130>(col4, colf, best, bl); }
    else if (s == 2) { conv_tile< 70>(col4, colf, best, bl);
                       conv_tile<115>(col4, colf, best, bl); }
    else             { conv_tile< 85>(col4, colf, best, bl);
                       conv_tile<100>(col4, colf, best, bl); }
    __syncthreads();                       // conv done: X now dead

    // ---- Phase F: cross-wave argmax + silent-check via aux rows ----
    Xa[s * 64 + f] = best;
    reinterpret_cast<int*>(Xa)[256 + s * 64 + f] = bl;
    Xa[512 + s * 64 + f] = pm;
    __syncthreads();

    if (s == 0) {
        float bv = Xa[f];
        int   L  = reinterpret_cast<int*>(Xa)[256 + f];
        #pragma unroll
        for (int c = 1; c < 4; ++c) {
            const float vv = Xa[c * 64 + f];
            const int   lv = reinterpret_cast<int*>(Xa)[256 + c * 64 + f];
            if (vv > bv || (vv == bv && lv < L)) { bv = vv; L = lv; }
        }
        const float mx = fmaxf(fmaxf(Xa[512 + f], Xa[512 + 64 + f]),
                               fmaxf(Xa[512 + 128 + f], Xa[512 + 192 + f]));
        const float pitch = SR_F / (float)L;
        out[(size_t)b * TFRAMES + t0 + f] = (mx < 1e-8f) ? 0.0f : pitch;
    }
}

extern "C" void kernel_launch(void* const* d_in, const int* in_sizes, int n_in,
                              void* d_out, int out_size, void* d_ws, size_t ws_size,
                              hipStream_t stream) {
    const float* audio = (const float*)d_in[0];
    float* out = (float*)d_out;
    pitch_kernel<<<dim3(1024), dim3(256), 0, stream>>>(audio, out);
}